// Round 10
// baseline (961.287 us; speedup 1.0000x reference)
//
#include <hip/hip_runtime.h>
#include <math.h>

#define TT 512
#define BB 128
#define KK 9

// ---------------------------------------------------------------------------
// fast activations: v_exp_f32 / v_rcp_f32 based (~1 ulp each)
// ---------------------------------------------------------------------------
__device__ __forceinline__ float fast_sigmoid(float x) {
    const float LOG2E = 1.4426950408889634f;
    float e = __builtin_amdgcn_exp2f(-x * LOG2E);
    return __builtin_amdgcn_rcpf(1.0f + e);
}
__device__ __forceinline__ float fast_tanh(float x) {
    const float LOG2E = 1.4426950408889634f;
    float a = fabsf(x);
    float e = __builtin_amdgcn_exp2f(-2.0f * a * LOG2E);   // in (0,1]
    float t = (1.0f - e) * __builtin_amdgcn_rcpf(1.0f + e);
    return copysignf(t, x);
}

// ---------------------------------------------------------------------------
// P: permute w_hh into the LSTM's thread-order, k-major layout so the
// lstm weight preload is FULLY COALESCED (R9 lesson: the scattered preload
// -- lane j reading its own 512B-distant row -> 64 lines/dwordx4 -- is the
// dominant per-dispatch fixed cost).
// wperm[dir][qq4][j][c] = w_hh_dir[r(j)][qq4*4+c],
//   r(j) = q*128 + w*16 + m   (j = w*64 + l, m = l>>2, q = l&3)
// ---------------------------------------------------------------------------
__global__ __launch_bounds__(256) void permute_whh(
    const float* __restrict__ w_hh_f, const float* __restrict__ w_hh_b,
    float* __restrict__ wperm)
{
    const int idx = blockIdx.x * 256 + threadIdx.x;   // 0..32767
    const int j   = idx & 511;
    const int qq4 = (idx >> 9) & 31;
    const int dir = idx >> 14;
    const float* whh = dir ? w_hh_b : w_hh_f;
    const int w_ = j >> 6, l = j & 63, m = l >> 2, q = l & 3;
    const int r = q * 128 + w_ * 16 + m;
    float4 v = *(const float4*)(whh + (size_t)r * 128 + qq4 * 4);
    *(float4*)(wperm + (size_t)idx * 4) = v;
}

// ---------------------------------------------------------------------------
// G: input projection, BK=32 chunked for occupancy (R8: whole-K 139 KB LDS
// -> 1 block/CU). LDS 33.8 KB -> 3 blocks/CU at __launch_bounds__(256,3).
// Coalesced staging, register prefetch of next chunk post-barrier, R2's
// zero-conflict fragment pattern. Embedding gather fused.
// ---------------------------------------------------------------------------
__global__ __launch_bounds__(256, 3) void input_gemm(
    const int* __restrict__ x, const float* __restrict__ emb,
    const float* __restrict__ w_ih_f, const float* __restrict__ w_ih_b,
    const float* __restrict__ b_ih_f, const float* __restrict__ b_hh_f,
    const float* __restrict__ b_ih_b, const float* __restrict__ b_hh_b,
    float* __restrict__ buf_f, float* __restrict__ buf_b,
    int t0f, int t0b)
{
    const int dir = blockIdx.z;
    const int s   = blockIdx.x;           // local timestep within chunk
    const int n0  = blockIdx.y * 128;     // gate tile base
    const int t   = (dir ? t0b : t0f) + s;
    const float* w  = dir ? w_ih_b : w_ih_f;
    const float* bi = dir ? b_ih_b : b_ih_f;
    const float* bh = dir ? b_hh_b : b_hh_f;
    float* dst = dir ? buf_b : buf_f;

    __shared__ __align__(16) float As[32][132];   // [k][row] 16.9 KB
    __shared__ __align__(16) float Bs[32][132];   // [k][gate] 16.9 KB

    const int tid  = threadIdx.x;
    const int lrow = tid >> 3;            // 0..31
    const int k4   = (tid & 7) * 4;       // 0..28

    int tokr[4];
    #pragma unroll
    for (int p = 0; p < 4; p++) tokr[p] = x[(p * 32 + lrow) * TT + t];

    const int tx = tid & 15;
    const int ty = tid >> 4;

    float acc[8][8];
    #pragma unroll
    for (int i = 0; i < 8; i++)
        #pragma unroll
        for (int j = 0; j < 8; j++) acc[i][j] = 0.0f;

    float4 aS[4], bS[4];
    #pragma unroll
    for (int p = 0; p < 4; p++) {
        aS[p] = *(const float4*)(emb + (size_t)tokr[p] * 128 + k4);
        bS[p] = *(const float4*)(w + (size_t)(n0 + p * 32 + lrow) * 128 + k4);
    }

    for (int kc = 0; kc < 128; kc += 32) {
        __syncthreads();                 // prev chunk's reads done
        #pragma unroll
        for (int p = 0; p < 4; p++) {
            const int row = p * 32 + lrow;
            As[k4 + 0][row] = aS[p].x; As[k4 + 1][row] = aS[p].y;
            As[k4 + 2][row] = aS[p].z; As[k4 + 3][row] = aS[p].w;
            Bs[k4 + 0][row] = bS[p].x; Bs[k4 + 1][row] = bS[p].y;
            Bs[k4 + 2][row] = bS[p].z; Bs[k4 + 3][row] = bS[p].w;
        }
        __syncthreads();                 // staging visible
        if (kc + 32 < 128) {             // prefetch next chunk (hidden by compute)
            #pragma unroll
            for (int p = 0; p < 4; p++) {
                aS[p] = *(const float4*)(emb + (size_t)tokr[p] * 128 + kc + 32 + k4);
                bS[p] = *(const float4*)(w + (size_t)(n0 + p * 32 + lrow) * 128 + kc + 32 + k4);
            }
        }
        #pragma unroll 8
        for (int k = 0; k < 32; k++) {
            float4 af0 = *(const float4*)&As[k][ty * 8];
            float4 af1 = *(const float4*)&As[k][ty * 8 + 4];
            float4 bf0 = *(const float4*)&Bs[k][tx * 8];
            float4 bf1 = *(const float4*)&Bs[k][tx * 8 + 4];
            float a_[8] = {af0.x, af0.y, af0.z, af0.w, af1.x, af1.y, af1.z, af1.w};
            float b_[8] = {bf0.x, bf0.y, bf0.z, bf0.w, bf1.x, bf1.y, bf1.z, bf1.w};
            #pragma unroll
            for (int i = 0; i < 8; i++)
                #pragma unroll
                for (int j = 0; j < 8; j++)
                    acc[i][j] += a_[i] * b_[j];
        }
    }

    const int nbase = n0 + tx * 8;
    float bias[8];
    #pragma unroll
    for (int j = 0; j < 8; j++) {
        int n = nbase + j;
        bias[j] = bi[n] + bh[n];
    }
    #pragma unroll
    for (int i = 0; i < 8; i++) {
        int brow = ty * 8 + i;
        float* o = dst + ((size_t)s * 128 + brow) * 512 + nbase;
        float4 v0, v1;
        v0.x = acc[i][0] + bias[0]; v0.y = acc[i][1] + bias[1];
        v0.z = acc[i][2] + bias[2]; v0.w = acc[i][3] + bias[3];
        v1.x = acc[i][4] + bias[4]; v1.y = acc[i][5] + bias[5];
        v1.z = acc[i][6] + bias[6]; v1.w = acc[i][7] + bias[7];
        *(float4*)o = v0;
        *(float4*)(o + 4) = v1;
    }
}

// ---------------------------------------------------------------------------
// L: LSTM recurrence, one block (512 thr, 8 waves) per (dir, batch-row).
// Gate-group layout: lanes {4m..4m+3} of wave w hold gates {i,f,g,o} of
// h-index k = w*16+m. 128 weights/thread from the PERMUTED layout
// (coalesced preload -- R9 lesson), dot fully unrolled (R3 lesson). ONE
// barrier per step; global ops issued POST-barrier (R6 lesson).
// ---------------------------------------------------------------------------
__global__ __launch_bounds__(512, 2) void lstm_chunk(
    const float* __restrict__ buf_f, const float* __restrict__ buf_b,
    const float* __restrict__ wperm,
    float* __restrict__ h_all,
    float* __restrict__ h_state, float* __restrict__ c_state,
    int t0f, int t0b, int C, int init)
{
    const int dir = blockIdx.x >> 7;
    const int b   = blockIdx.x & 127;
    const int j   = threadIdx.x;
    const int w_  = j >> 6;          // wave id 0..7
    const int l   = j & 63;
    const int m   = l >> 2;          // group 0..15
    const int q   = l & 3;           // gate: 0=i 1=f 2=g 3=o
    const int k   = w_ * 16 + m;     // h index 0..127
    const int r   = q * 128 + k;     // gate row in [0,512)

    // coalesced weight preload: lane-consecutive 16B per instruction
    const float* wp = wperm + (size_t)dir * 65536 + (size_t)j * 4;
    float wR[128];
    #pragma unroll
    for (int qq = 0; qq < 32; qq++) {
        float4 v = *(const float4*)(wp + (size_t)qq * 2048);
        wR[4*qq+0] = v.x; wR[4*qq+1] = v.y; wR[4*qq+2] = v.z; wR[4*qq+3] = v.w;
    }

    __shared__ __align__(16) float h_lds[2][128];
    float c;
    if (init) {
        c = 0.0f;
        if (q == 0) h_lds[0][k] = 0.0f;
    } else {
        c = c_state[((size_t)dir * 128 + b) * 128 + k];
        if (q == 0) h_lds[0][k] = h_state[((size_t)dir * 128 + b) * 128 + k];
    }
    __syncthreads();

    const float* buf = dir ? buf_b : buf_f;
    const int t0     = dir ? t0b : t0f;
    const int  tl0   = dir ? (C - 1) : 0;
    const long lstep = dir ? -(long)(128 * 512) : (long)(128 * 512);

    const float* xp = buf + ((size_t)tl0 * 128 + b) * 512 + r;
    float xw = *xp;
    float h_reg = 0.0f;

    for (int s = 0; s < C; s++) {
        const int t = t0 + (dir ? (C - 1 - s) : s);
        const int p = s & 1;
        const float* hprev = h_lds[p];

        float a0 = 0.f, a1 = 0.f, a2 = 0.f, a3 = 0.f;
        #pragma unroll
        for (int qq = 0; qq < 32; qq++) {
            float4 h4 = *(const float4*)&hprev[4 * qq];
            a0 += wR[4*qq+0] * h4.x;
            a1 += wR[4*qq+1] * h4.y;
            a2 += wR[4*qq+2] * h4.z;
            a3 += wR[4*qq+3] * h4.w;
        }
        float pre = xw + ((a0 + a1) + (a2 + a3));

        float act = (q == 2) ? fast_tanh(pre) : fast_sigmoid(pre);

        float f_ = __shfl_xor(act, 1);   // q0 <- q1 (f)
        float g_ = __shfl_xor(act, 2);   // q0 <- q2 (g)
        float o_ = __shfl_xor(act, 3);   // q0 <- q3 (o)

        c = f_ * c + act * g_;           // act == i on q0
        h_reg = o_ * fast_tanh(c);
        if (q == 0) h_lds[p ^ 1][k] = h_reg;

        __syncthreads();                 // h_t visible to all waves

        // post-barrier: issue global ops with a full step of slack
        if (s + 1 < C) { xp += lstep; xw = *xp; }
        if (q == 0)
            h_all[((size_t)t * BB + b) * 256 + dir * 128 + k] = h_reg;
    }

    if (q == 0) {
        h_state[((size_t)dir * 128 + b) * 128 + k] = h_reg;
        c_state[((size_t)dir * 128 + b) * 128 + k] = c;
    }
}

// ---------------------------------------------------------------------------
// M: emissions = h_all @ W_tag^T + b_tag. One wave per (t,b) row.
// ---------------------------------------------------------------------------
__global__ __launch_bounds__(256) void emis_kernel(
    const float* __restrict__ h_all, const float* __restrict__ W_tag,
    const float* __restrict__ b_tag, float* __restrict__ em_sum)
{
    const int wid  = threadIdx.x >> 6;
    const int lane = threadIdx.x & 63;
    const size_t m = (size_t)blockIdx.x * 4 + wid;   // row = t*B + b
    const float4 hv = *(const float4*)(h_all + m * 256 + lane * 4);
    #pragma unroll
    for (int kk = 0; kk < KK; kk++) {
        const float4 wv = *(const float4*)(W_tag + kk * 256 + lane * 4);
        float p = hv.x * wv.x + hv.y * wv.y + hv.z * wv.z + hv.w * wv.w;
        #pragma unroll
        for (int off = 32; off > 0; off >>= 1) p += __shfl_down(p, off);
        if (lane == 0) em_sum[m * KK + kk] = p + b_tag[kk];
    }
}

// ---------------------------------------------------------------------------
// V: Viterbi decode. One block (64 threads) per batch row. Tournament max
// tree (strict-> right-wins == jnp.argmax first-index ties); em prefetch
// off the serial critical path.
// ---------------------------------------------------------------------------
__device__ __forceinline__ void vmax(float va, int ia, float vb, int ib,
                                     float& vo, int& io) {
    bool gt = vb > va;
    vo = gt ? vb : va;
    io = gt ? ib : ia;
}

__global__ __launch_bounds__(64) void viterbi_kernel(
    const float* __restrict__ em_sum,
    const float* __restrict__ start_trans, const float* __restrict__ end_trans,
    const float* __restrict__ trans, int* __restrict__ out)
{
    const int b = blockIdx.x;
    const int lane = threadIdx.x;
    __shared__ float em_s[TT * KK];
    __shared__ unsigned char bp[TT][KK];

    for (int f = lane; f < TT * KK; f += 64) {
        int t = f / KK, kk = f - t * KK;
        em_s[f] = em_sum[((size_t)t * BB + b) * KK + kk];
    }
    __syncthreads();

    float trans_col[KK];
    float score = -1e30f;
    if (lane < KK) {
        #pragma unroll
        for (int i = 0; i < KK; i++) trans_col[i] = trans[i * KK + lane];
        score = start_trans[lane] + em_s[lane];
    }

    float em_cur = (lane < KK) ? em_s[KK + lane] : 0.0f;   // t=1
    for (int t = 1; t < TT; t++) {
        float em_next = (t + 1 < TT && lane < KK) ? em_s[(t + 1) * KK + lane] : 0.0f;

        float my = (lane < KK) ? score : -1e30f;
        float cand[KK];
        #pragma unroll
        for (int i = 0; i < KK; i++) cand[i] = __shfl(my, i) + trans_col[i];

        float v01, v23, v45, v67, v03, v47, v07, vb_;
        int   i01, i23, i45, i67, i03, i47, i07, ib_;
        vmax(cand[0], 0, cand[1], 1, v01, i01);
        vmax(cand[2], 2, cand[3], 3, v23, i23);
        vmax(cand[4], 4, cand[5], 5, v45, i45);
        vmax(cand[6], 6, cand[7], 7, v67, i67);
        vmax(v01, i01, v23, i23, v03, i03);
        vmax(v45, i45, v67, i67, v47, i47);
        vmax(v03, i03, v47, i47, v07, i07);
        vmax(v07, i07, cand[8], 8, vb_, ib_);

        if (lane < KK) {
            bp[t][lane] = (unsigned char)ib_;
            score = vb_ + em_cur;
        }
        em_cur = em_next;
    }

    float fin = (lane < KK) ? (score + end_trans[lane]) : -1e30f;
    float farr[KK];
    #pragma unroll
    for (int jx = 0; jx < KK; jx++) farr[jx] = __shfl(fin, jx);
    float v01, v23, v45, v67, v03, v47, v07, vb_;
    int   i01, i23, i45, i67, i03, i47, i07, bj;
    vmax(farr[0], 0, farr[1], 1, v01, i01);
    vmax(farr[2], 2, farr[3], 3, v23, i23);
    vmax(farr[4], 4, farr[5], 5, v45, i45);
    vmax(farr[6], 6, farr[7], 7, v67, i67);
    vmax(v01, i01, v23, i23, v03, i03);
    vmax(v45, i45, v67, i67, v47, i47);
    vmax(v03, i03, v47, i47, v07, i07);
    vmax(v07, i07, farr[8], 8, vb_, bj);

    if (lane == 0) {
        int tag = bj;
        out[b * TT + (TT - 1)] = tag;
        for (int t = TT - 1; t >= 1; t--) {
            tag = bp[t][tag];
            out[b * TT + t - 1] = tag;
        }
    }
}

// ---------------------------------------------------------------------------
extern "C" void kernel_launch(void* const* d_in, const int* in_sizes, int n_in,
                              void* d_out, int out_size, void* d_ws, size_t ws_size,
                              hipStream_t stream)
{
    const int*   x       = (const int*)  d_in[0];
    const float* emb     = (const float*)d_in[1];
    const float* w_ih_f  = (const float*)d_in[2];
    const float* w_hh_f  = (const float*)d_in[3];
    const float* b_ih_f  = (const float*)d_in[4];
    const float* b_hh_f  = (const float*)d_in[5];
    const float* w_ih_b  = (const float*)d_in[6];
    const float* w_hh_b  = (const float*)d_in[7];
    const float* b_ih_b  = (const float*)d_in[8];
    const float* b_hh_b  = (const float*)d_in[9];
    const float* W_tag   = (const float*)d_in[10];
    const float* b_tag   = (const float*)d_in[11];
    const float* start_t = (const float*)d_in[12];
    const float* end_t   = (const float*)d_in[13];
    const float* trans   = (const float*)d_in[14];
    int* out = (int*)d_out;

    // fixed-size pieces (floats)
    const size_t hall_elems  = (size_t)TT * BB * 256;  // 67 MB
    const size_t em_elems    = (size_t)TT * BB * KK;   // 2.25 MB
    const size_t state_elems = (size_t)2 * 128 * 128;
    const size_t wperm_elems = (size_t)2 * 32 * 512 * 4;  // 131072

    // C=512 preferred: single lstm dispatch (R9 lesson: per-dispatch fixed
    // cost ~90 us makes chunking lose; 4x131.6 vs 1x250).
    int C = 32;
    const int cands[5] = {512, 256, 128, 64, 32};
    for (int ci = 0; ci < 5; ci++) {
        size_t need = ((size_t)2 * cands[ci] * BB * 512
                       + hall_elems + em_elems
                       + 2 * state_elems + wperm_elems) * sizeof(float);
        if (ws_size >= need) { C = cands[ci]; break; }
    }

    float* buf_f   = (float*)d_ws;                       // C*128*512
    float* buf_b   = buf_f + (size_t)C * BB * 512;       // C*128*512
    float* em_sum  = buf_b + (size_t)C * BB * 512;       // T*B*9
    float* h_state = em_sum + em_elems;                  // 2*128*128
    float* c_state = h_state + state_elems;              // 2*128*128
    float* h_all   = c_state + state_elems;              // T*B*256
    float* wperm   = h_all + hall_elems;                 // 2*32*512*4

    permute_whh<<<dim3(128), dim3(256), 0, stream>>>(w_hh_f, w_hh_b, wperm);

    const int rounds = TT / C;
    for (int r = 0; r < rounds; r++) {
        const int t0f = r * C;
        const int t0b = TT - (r + 1) * C;
        dim3 gg(C, 4, 2);
        input_gemm<<<gg, dim3(256), 0, stream>>>(
            x, emb, w_ih_f, w_ih_b, b_ih_f, b_hh_f, b_ih_b, b_hh_b,
            buf_f, buf_b, t0f, t0b);
        lstm_chunk<<<dim3(256), dim3(512), 0, stream>>>(
            buf_f, buf_b, wperm, h_all,
            h_state, c_state, t0f, t0b, C, (r == 0) ? 1 : 0);
    }
    emis_kernel<<<dim3((TT * BB) / 4), dim3(256), 0, stream>>>(
        h_all, W_tag, b_tag, em_sum);
    viterbi_kernel<<<dim3(BB), dim3(64), 0, stream>>>(
        em_sum, start_t, end_t, trans, out);
}

// Round 11
// 899.021 us; speedup vs baseline: 1.0693x; 1.0693x over previous
//
#include <hip/hip_runtime.h>
#include <math.h>

#define TT 512
#define BB 128
#define KK 9

// ---------------------------------------------------------------------------
// fast activations: v_exp_f32 / v_rcp_f32 based (~1 ulp each)
// ---------------------------------------------------------------------------
__device__ __forceinline__ float fast_sigmoid(float x) {
    const float LOG2E = 1.4426950408889634f;
    float e = __builtin_amdgcn_exp2f(-x * LOG2E);
    return __builtin_amdgcn_rcpf(1.0f + e);
}
__device__ __forceinline__ float fast_tanh(float x) {
    const float LOG2E = 1.4426950408889634f;
    float a = fabsf(x);
    float e = __builtin_amdgcn_exp2f(-2.0f * a * LOG2E);   // in (0,1]
    float t = (1.0f - e) * __builtin_amdgcn_rcpf(1.0f + e);
    return copysignf(t, x);
}

// ---------------------------------------------------------------------------
// G: input projection, BK=32 chunked for occupancy (R8: whole-K 139 KB LDS
// -> 1 block/CU). LDS 33.8 KB -> 3 blocks/CU at __launch_bounds__(256,3).
// Coalesced staging, register prefetch of next chunk post-barrier, R2's
// zero-conflict fragment pattern. Embedding gather fused.
// ---------------------------------------------------------------------------
__global__ __launch_bounds__(256, 3) void input_gemm(
    const int* __restrict__ x, const float* __restrict__ emb,
    const float* __restrict__ w_ih_f, const float* __restrict__ w_ih_b,
    const float* __restrict__ b_ih_f, const float* __restrict__ b_hh_f,
    const float* __restrict__ b_ih_b, const float* __restrict__ b_hh_b,
    float* __restrict__ buf_f, float* __restrict__ buf_b,
    int t0f, int t0b)
{
    const int dir = blockIdx.z;
    const int s   = blockIdx.x;           // local timestep within chunk
    const int n0  = blockIdx.y * 128;     // gate tile base
    const int t   = (dir ? t0b : t0f) + s;
    const float* w  = dir ? w_ih_b : w_ih_f;
    const float* bi = dir ? b_ih_b : b_ih_f;
    const float* bh = dir ? b_hh_b : b_hh_f;
    float* dst = dir ? buf_b : buf_f;

    __shared__ __align__(16) float As[32][132];   // [k][row] 16.9 KB
    __shared__ __align__(16) float Bs[32][132];   // [k][gate] 16.9 KB

    const int tid  = threadIdx.x;
    const int lrow = tid >> 3;            // 0..31
    const int k4   = (tid & 7) * 4;       // 0..28

    int tokr[4];
    #pragma unroll
    for (int p = 0; p < 4; p++) tokr[p] = x[(p * 32 + lrow) * TT + t];

    const int tx = tid & 15;
    const int ty = tid >> 4;

    float acc[8][8];
    #pragma unroll
    for (int i = 0; i < 8; i++)
        #pragma unroll
        for (int j = 0; j < 8; j++) acc[i][j] = 0.0f;

    float4 aS[4], bS[4];
    #pragma unroll
    for (int p = 0; p < 4; p++) {
        aS[p] = *(const float4*)(emb + (size_t)tokr[p] * 128 + k4);
        bS[p] = *(const float4*)(w + (size_t)(n0 + p * 32 + lrow) * 128 + k4);
    }

    for (int kc = 0; kc < 128; kc += 32) {
        __syncthreads();                 // prev chunk's reads done
        #pragma unroll
        for (int p = 0; p < 4; p++) {
            const int row = p * 32 + lrow;
            As[k4 + 0][row] = aS[p].x; As[k4 + 1][row] = aS[p].y;
            As[k4 + 2][row] = aS[p].z; As[k4 + 3][row] = aS[p].w;
            Bs[k4 + 0][row] = bS[p].x; Bs[k4 + 1][row] = bS[p].y;
            Bs[k4 + 2][row] = bS[p].z; Bs[k4 + 3][row] = bS[p].w;
        }
        __syncthreads();                 // staging visible
        if (kc + 32 < 128) {             // prefetch next chunk (hidden by compute)
            #pragma unroll
            for (int p = 0; p < 4; p++) {
                aS[p] = *(const float4*)(emb + (size_t)tokr[p] * 128 + kc + 32 + k4);
                bS[p] = *(const float4*)(w + (size_t)(n0 + p * 32 + lrow) * 128 + kc + 32 + k4);
            }
        }
        #pragma unroll 8
        for (int k = 0; k < 32; k++) {
            float4 af0 = *(const float4*)&As[k][ty * 8];
            float4 af1 = *(const float4*)&As[k][ty * 8 + 4];
            float4 bf0 = *(const float4*)&Bs[k][tx * 8];
            float4 bf1 = *(const float4*)&Bs[k][tx * 8 + 4];
            float a_[8] = {af0.x, af0.y, af0.z, af0.w, af1.x, af1.y, af1.z, af1.w};
            float b_[8] = {bf0.x, bf0.y, bf0.z, bf0.w, bf1.x, bf1.y, bf1.z, bf1.w};
            #pragma unroll
            for (int i = 0; i < 8; i++)
                #pragma unroll
                for (int j = 0; j < 8; j++)
                    acc[i][j] += a_[i] * b_[j];
        }
    }

    const int nbase = n0 + tx * 8;
    float bias[8];
    #pragma unroll
    for (int j = 0; j < 8; j++) {
        int n = nbase + j;
        bias[j] = bi[n] + bh[n];
    }
    #pragma unroll
    for (int i = 0; i < 8; i++) {
        int brow = ty * 8 + i;
        float* o = dst + ((size_t)s * 128 + brow) * 512 + nbase;
        float4 v0, v1;
        v0.x = acc[i][0] + bias[0]; v0.y = acc[i][1] + bias[1];
        v0.z = acc[i][2] + bias[2]; v0.w = acc[i][3] + bias[3];
        v1.x = acc[i][4] + bias[4]; v1.y = acc[i][5] + bias[5];
        v1.z = acc[i][6] + bias[6]; v1.w = acc[i][7] + bias[7];
        *(float4*)o = v0;
        *(float4*)(o + 4) = v1;
    }
}

// ---------------------------------------------------------------------------
// L: LSTM recurrence, one block (512 thr, 8 waves) per (dir, batch-row).
// Gate-group layout: lanes {4m..4m+3} of wave w hold gates {i,f,g,o} of
// h-index k = w*16+m. 128 weights/thread loaded DIRECTLY from w_hh
// (R10 lesson: ws-permuted "coalesced" preload measured SLOWER, 282 vs
// 250 us -- the scattered preload is L2-hot and costs ~8 us, not 90).
// Dot fully unrolled (R3: partial unroll -> scratch). ONE barrier per
// step; global ops issued POST-barrier (R6: pre-barrier global ops put
// the vmcnt(0) drain on the critical path). 3 independent shfl_xor.
// ---------------------------------------------------------------------------
__global__ __launch_bounds__(512, 2) void lstm_chunk(
    const float* __restrict__ buf_f, const float* __restrict__ buf_b,
    const float* __restrict__ w_hh_f, const float* __restrict__ w_hh_b,
    float* __restrict__ h_all,
    float* __restrict__ h_state, float* __restrict__ c_state,
    int t0f, int t0b, int C, int init)
{
    const int dir = blockIdx.x >> 7;
    const int b   = blockIdx.x & 127;
    const int j   = threadIdx.x;
    const int w_  = j >> 6;          // wave id 0..7
    const int l   = j & 63;
    const int m   = l >> 2;          // group 0..15
    const int q   = l & 3;           // gate: 0=i 1=f 2=g 3=o
    const int k   = w_ * 16 + m;     // h index 0..127
    const int r   = q * 128 + k;     // gate row in [0,512)

    const float* whh = dir ? w_hh_b : w_hh_f;
    float wR[128];
    #pragma unroll
    for (int qq = 0; qq < 32; qq++) {
        float4 v = *(const float4*)(whh + (size_t)r * 128 + qq * 4);
        wR[4*qq+0] = v.x; wR[4*qq+1] = v.y; wR[4*qq+2] = v.z; wR[4*qq+3] = v.w;
    }

    __shared__ __align__(16) float h_lds[2][128];
    float c;
    if (init) {
        c = 0.0f;
        if (q == 0) h_lds[0][k] = 0.0f;
    } else {
        c = c_state[((size_t)dir * 128 + b) * 128 + k];
        if (q == 0) h_lds[0][k] = h_state[((size_t)dir * 128 + b) * 128 + k];
    }
    __syncthreads();

    const float* buf = dir ? buf_b : buf_f;
    const int t0     = dir ? t0b : t0f;
    const int  tl0   = dir ? (C - 1) : 0;
    const long lstep = dir ? -(long)(128 * 512) : (long)(128 * 512);

    const float* xp = buf + ((size_t)tl0 * 128 + b) * 512 + r;
    float xw = *xp;
    float h_reg = 0.0f;

    for (int s = 0; s < C; s++) {
        const int t = t0 + (dir ? (C - 1 - s) : s);
        const int p = s & 1;
        const float* hprev = h_lds[p];

        float a0 = 0.f, a1 = 0.f, a2 = 0.f, a3 = 0.f;
        #pragma unroll
        for (int qq = 0; qq < 32; qq++) {
            float4 h4 = *(const float4*)&hprev[4 * qq];
            a0 += wR[4*qq+0] * h4.x;
            a1 += wR[4*qq+1] * h4.y;
            a2 += wR[4*qq+2] * h4.z;
            a3 += wR[4*qq+3] * h4.w;
        }
        float pre = xw + ((a0 + a1) + (a2 + a3));

        float act = (q == 2) ? fast_tanh(pre) : fast_sigmoid(pre);

        float f_ = __shfl_xor(act, 1);   // q0 <- q1 (f)
        float g_ = __shfl_xor(act, 2);   // q0 <- q2 (g)
        float o_ = __shfl_xor(act, 3);   // q0 <- q3 (o)

        c = f_ * c + act * g_;           // act == i on q0
        h_reg = o_ * fast_tanh(c);
        if (q == 0) h_lds[p ^ 1][k] = h_reg;

        __syncthreads();                 // h_t visible to all waves

        // post-barrier: issue global ops with a full step of slack
        if (s + 1 < C) { xp += lstep; xw = *xp; }
        if (q == 0)
            h_all[((size_t)t * BB + b) * 256 + dir * 128 + k] = h_reg;
    }

    if (q == 0) {
        h_state[((size_t)dir * 128 + b) * 128 + k] = h_reg;
        c_state[((size_t)dir * 128 + b) * 128 + k] = c;
    }
}

// ---------------------------------------------------------------------------
// M: emissions = h_all @ W_tag^T + b_tag. One wave per (t,b) row.
// ---------------------------------------------------------------------------
__global__ __launch_bounds__(256) void emis_kernel(
    const float* __restrict__ h_all, const float* __restrict__ W_tag,
    const float* __restrict__ b_tag, float* __restrict__ em_sum)
{
    const int wid  = threadIdx.x >> 6;
    const int lane = threadIdx.x & 63;
    const size_t m = (size_t)blockIdx.x * 4 + wid;   // row = t*B + b
    const float4 hv = *(const float4*)(h_all + m * 256 + lane * 4);
    #pragma unroll
    for (int kk = 0; kk < KK; kk++) {
        const float4 wv = *(const float4*)(W_tag + kk * 256 + lane * 4);
        float p = hv.x * wv.x + hv.y * wv.y + hv.z * wv.z + hv.w * wv.w;
        #pragma unroll
        for (int off = 32; off > 0; off >>= 1) p += __shfl_down(p, off);
        if (lane == 0) em_sum[m * KK + kk] = p + b_tag[kk];
    }
}

// ---------------------------------------------------------------------------
// V: Viterbi decode. One block (64 threads) per batch row. Tournament max
// tree (strict-> right-wins == jnp.argmax first-index ties); em prefetch
// off the serial critical path.
// ---------------------------------------------------------------------------
__device__ __forceinline__ void vmax(float va, int ia, float vb, int ib,
                                     float& vo, int& io) {
    bool gt = vb > va;
    vo = gt ? vb : va;
    io = gt ? ib : ia;
}

__global__ __launch_bounds__(64) void viterbi_kernel(
    const float* __restrict__ em_sum,
    const float* __restrict__ start_trans, const float* __restrict__ end_trans,
    const float* __restrict__ trans, int* __restrict__ out)
{
    const int b = blockIdx.x;
    const int lane = threadIdx.x;
    __shared__ float em_s[TT * KK];
    __shared__ unsigned char bp[TT][KK];

    for (int f = lane; f < TT * KK; f += 64) {
        int t = f / KK, kk = f - t * KK;
        em_s[f] = em_sum[((size_t)t * BB + b) * KK + kk];
    }
    __syncthreads();

    float trans_col[KK];
    float score = -1e30f;
    if (lane < KK) {
        #pragma unroll
        for (int i = 0; i < KK; i++) trans_col[i] = trans[i * KK + lane];
        score = start_trans[lane] + em_s[lane];
    }

    float em_cur = (lane < KK) ? em_s[KK + lane] : 0.0f;   // t=1
    for (int t = 1; t < TT; t++) {
        float em_next = (t + 1 < TT && lane < KK) ? em_s[(t + 1) * KK + lane] : 0.0f;

        float my = (lane < KK) ? score : -1e30f;
        float cand[KK];
        #pragma unroll
        for (int i = 0; i < KK; i++) cand[i] = __shfl(my, i) + trans_col[i];

        float v01, v23, v45, v67, v03, v47, v07, vb_;
        int   i01, i23, i45, i67, i03, i47, i07, ib_;
        vmax(cand[0], 0, cand[1], 1, v01, i01);
        vmax(cand[2], 2, cand[3], 3, v23, i23);
        vmax(cand[4], 4, cand[5], 5, v45, i45);
        vmax(cand[6], 6, cand[7], 7, v67, i67);
        vmax(v01, i01, v23, i23, v03, i03);
        vmax(v45, i45, v67, i67, v47, i47);
        vmax(v03, i03, v47, i47, v07, i07);
        vmax(v07, i07, cand[8], 8, vb_, ib_);

        if (lane < KK) {
            bp[t][lane] = (unsigned char)ib_;
            score = vb_ + em_cur;
        }
        em_cur = em_next;
    }

    float fin = (lane < KK) ? (score + end_trans[lane]) : -1e30f;
    float farr[KK];
    #pragma unroll
    for (int jx = 0; jx < KK; jx++) farr[jx] = __shfl(fin, jx);
    float v01, v23, v45, v67, v03, v47, v07, vb_;
    int   i01, i23, i45, i67, i03, i47, i07, bj;
    vmax(farr[0], 0, farr[1], 1, v01, i01);
    vmax(farr[2], 2, farr[3], 3, v23, i23);
    vmax(farr[4], 4, farr[5], 5, v45, i45);
    vmax(farr[6], 6, farr[7], 7, v67, i67);
    vmax(v01, i01, v23, i23, v03, i03);
    vmax(v45, i45, v67, i67, v47, i47);
    vmax(v03, i03, v47, i47, v07, i07);
    vmax(v07, i07, farr[8], 8, vb_, bj);

    if (lane == 0) {
        int tag = bj;
        out[b * TT + (TT - 1)] = tag;
        for (int t = TT - 1; t >= 1; t--) {
            tag = bp[t][tag];
            out[b * TT + t - 1] = tag;
        }
    }
}

// ---------------------------------------------------------------------------
extern "C" void kernel_launch(void* const* d_in, const int* in_sizes, int n_in,
                              void* d_out, int out_size, void* d_ws, size_t ws_size,
                              hipStream_t stream)
{
    const int*   x       = (const int*)  d_in[0];
    const float* emb     = (const float*)d_in[1];
    const float* w_ih_f  = (const float*)d_in[2];
    const float* w_hh_f  = (const float*)d_in[3];
    const float* b_ih_f  = (const float*)d_in[4];
    const float* b_hh_f  = (const float*)d_in[5];
    const float* w_ih_b  = (const float*)d_in[6];
    const float* w_hh_b  = (const float*)d_in[7];
    const float* b_ih_b  = (const float*)d_in[8];
    const float* b_hh_b  = (const float*)d_in[9];
    const float* W_tag   = (const float*)d_in[10];
    const float* b_tag   = (const float*)d_in[11];
    const float* start_t = (const float*)d_in[12];
    const float* end_t   = (const float*)d_in[13];
    const float* trans   = (const float*)d_in[14];
    int* out = (int*)d_out;

    // fixed-size pieces (floats)
    const size_t hall_elems  = (size_t)TT * BB * 256;  // 67 MB
    const size_t em_elems    = (size_t)TT * BB * KK;   // 2.25 MB
    const size_t state_elems = (size_t)2 * 128 * 128;

    // C=512 preferred: single lstm dispatch (R9: per-dispatch fixed cost
    // ~70-90 us makes chunking lose; 4x131.6 vs 1x250).
    int C = 32;
    const int cands[5] = {512, 256, 128, 64, 32};
    for (int ci = 0; ci < 5; ci++) {
        size_t need = ((size_t)2 * cands[ci] * BB * 512
                       + hall_elems + em_elems
                       + 2 * state_elems) * sizeof(float);
        if (ws_size >= need) { C = cands[ci]; break; }
    }

    float* buf_f   = (float*)d_ws;                       // C*128*512
    float* buf_b   = buf_f + (size_t)C * BB * 512;       // C*128*512
    float* em_sum  = buf_b + (size_t)C * BB * 512;       // T*B*9
    float* h_state = em_sum + em_elems;                  // 2*128*128
    float* c_state = h_state + state_elems;              // 2*128*128
    float* h_all   = c_state + state_elems;              // T*B*256

    const int rounds = TT / C;
    for (int r = 0; r < rounds; r++) {
        const int t0f = r * C;
        const int t0b = TT - (r + 1) * C;
        dim3 gg(C, 4, 2);
        input_gemm<<<gg, dim3(256), 0, stream>>>(
            x, emb, w_ih_f, w_ih_b, b_ih_f, b_hh_f, b_ih_b, b_hh_b,
            buf_f, buf_b, t0f, t0b);
        lstm_chunk<<<dim3(256), dim3(512), 0, stream>>>(
            buf_f, buf_b, w_hh_f, w_hh_b, h_all,
            h_state, c_state, t0f, t0b, C, (r == 0) ? 1 : 0);
    }
    emis_kernel<<<dim3((TT * BB) / 4), dim3(256), 0, stream>>>(
        h_all, W_tag, b_tag, em_sum);
    viterbi_kernel<<<dim3(BB), dim3(64), 0, stream>>>(
        em_sum, start_t, end_t, trans, out);
}